// Round 5
// baseline (252.924 us; speedup 1.0000x reference)
//
#include <hip/hip_runtime.h>

#define T_SEQ 2048
#define NH 4
#define DH 64

typedef __bf16 bf16x8 __attribute__((ext_vector_type(8)));
typedef _Float16 f16x8 __attribute__((ext_vector_type(8)));
typedef _Float16 f16x2 __attribute__((ext_vector_type(2)));
typedef float f32x4 __attribute__((ext_vector_type(4)));
typedef unsigned short u16x8 __attribute__((ext_vector_type(8)));

__device__ __forceinline__ unsigned short f2bf_rne(float x) {
  unsigned int u = __builtin_bit_cast(unsigned int, x);
  u += 0x7fffu + ((u >> 16) & 1u);
  return (unsigned short)(u >> 16);
}
__device__ __forceinline__ float bf2f(unsigned short s) {
  unsigned int u = ((unsigned int)s) << 16;
  return __builtin_bit_cast(float, u);
}
__device__ __forceinline__ unsigned short f2h(float x) {
  _Float16 h = (_Float16)x;  // v_cvt_f16_f32, RNE
  return __builtin_bit_cast(unsigned short, h);
}

// ---------------------------------------------------------------------------
// prep_w: transpose + hi/lo split W (256x256 f32) -> WtHi/WtLo [n][k] bf16.
// ---------------------------------------------------------------------------
__global__ void prep_w(const float* __restrict__ W,
                       unsigned short* __restrict__ WtHi,
                       unsigned short* __restrict__ WtLo) {
  __shared__ float ls[32][65];
  const int tid = threadIdx.x;
  const int k0 = (blockIdx.x >> 2) * 32;
  const int n0 = (blockIdx.x & 3) * 64;
#pragma unroll
  for (int i = 0; i < 8; i++) {
    int e = i * 256 + tid;
    int r = e >> 6, c = e & 63;
    ls[r][c] = W[(k0 + r) * 256 + n0 + c];
  }
  __syncthreads();
  const int n = tid & 63;
  const int part = tid >> 6;
  u16x8 vh, vl;
#pragma unroll
  for (int j = 0; j < 8; j++) {
    float w = ls[part * 8 + j][n];
    unsigned short h16 = f2bf_rne(w);
    vh[j] = h16;
    vl[j] = f2bf_rne(w - bf2f(h16));
  }
  size_t dst = (size_t)(n0 + n) * 256 + k0 + part * 8;
  *(u16x8*)&WtHi[dst] = vh;
  *(u16x8*)&WtLo[dst] = vl;
}

// ---------------------------------------------------------------------------
// wh_gemm: Wh = h @ W via split-bf16 MFMA (3-term, ~fp32 accurate).
//   Kb[bh][t][d] = f16(Wh * sqrt(log2e/8))   (Q and K)
//   Vs[bh][d][sigma(t)] = f16(Wh)            (PV B-operand, key-permuted)
// ---------------------------------------------------------------------------
__global__ __launch_bounds__(256, 2) void wh_gemm(
    const float* __restrict__ h,
    const unsigned short* __restrict__ WtHi,
    const unsigned short* __restrict__ WtLo,
    unsigned short* __restrict__ Kb, unsigned short* __restrict__ Vs) {
  __shared__ __align__(16) unsigned short ktile[32][272];
  __shared__ __align__(16) unsigned short vtile[256][40];
  const int tid = threadIdx.x;
  const int wave = tid >> 6, lane = tid & 63, l15 = lane & 15, quad = lane >> 4;
  const int m0b = blockIdx.x * 32;
  const int m0 = m0b + (wave & 1) * 16;
  const int n0w = (wave >> 1) * 128;
  f32x4 acc[8];
#pragma unroll
  for (int nt = 0; nt < 8; nt++) acc[nt] = (f32x4){0.f, 0.f, 0.f, 0.f};

  for (int kc = 0; kc < 8; kc++) {
    const float4* hp = (const float4*)&h[(size_t)(m0 + l15) * 256 + kc * 32 + quad * 8];
    float4 a0 = hp[0], a1 = hp[1];
    float xs[8] = {a0.x, a0.y, a0.z, a0.w, a1.x, a1.y, a1.z, a1.w};
    u16x8 ah, al;
#pragma unroll
    for (int j = 0; j < 8; j++) {
      unsigned short h16 = f2bf_rne(xs[j]);
      ah[j] = h16;
      al[j] = f2bf_rne(xs[j] - bf2f(h16));
    }
    bf16x8 ahi = __builtin_bit_cast(bf16x8, ah);
    bf16x8 alo = __builtin_bit_cast(bf16x8, al);
#pragma unroll
    for (int nt = 0; nt < 8; nt++) {
      size_t wb = (size_t)(n0w + nt * 16 + l15) * 256 + kc * 32 + quad * 8;
      bf16x8 bhi = *(const bf16x8*)&WtHi[wb];
      bf16x8 blo = *(const bf16x8*)&WtLo[wb];
      acc[nt] = __builtin_amdgcn_mfma_f32_16x16x32_bf16(ahi, bhi, acc[nt], 0, 0, 0);
      acc[nt] = __builtin_amdgcn_mfma_f32_16x16x32_bf16(alo, bhi, acc[nt], 0, 0, 0);
      acc[nt] = __builtin_amdgcn_mfma_f32_16x16x32_bf16(ahi, blo, acc[nt], 0, 0, 0);
    }
  }
  const float s1 = 0.424664717f;  // sqrt(log2(e)/8)
  const int tl = (wave & 1) * 16 + quad * 4;
#pragma unroll
  for (int nt = 0; nt < 8; nt++) {
    int n = n0w + nt * 16 + l15;
    ushort4 vp;
#pragma unroll
    for (int r = 0; r < 4; r++) {
      float v = acc[nt][r];
      ktile[tl + r][n] = f2h(v * s1);
      ((unsigned short*)&vp)[r] = f2h(v);
    }
    *(uint2*)&vtile[n][tl] = __builtin_bit_cast(uint2, vp);
  }
  __syncthreads();
  {  // Kb out: 4 x b128 stores (natural t order)
    int t = tid >> 3, seg = tid & 7;
    int m = m0b + t, b = m >> 11, tt = m & 2047;
    int head = seg >> 1, d0 = (seg & 1) * 32;
    unsigned short* dst = &Kb[((size_t)(b * NH + head) * T_SEQ + tt) * DH + d0];
#pragma unroll
    for (int q = 0; q < 4; q++)
      *(u16x8*)&dst[q * 8] = *(const u16x8*)&ktile[t][seg * 32 + q * 8];
  }
  {  // Vs out: sigma order (pos g*32+quad*8+half*4+j <-> t g*32+half*16+quad*4+j)
    int n = tid, head = n >> 6, d = n & 63;
    int b = m0b >> 11, t0 = m0b & 2047;
    unsigned short* dst = &Vs[((size_t)(b * NH + head) * DH + d) * T_SEQ + t0];
#pragma unroll
    for (int q = 0; q < 4; q++) {
      uint2 lo = *(const uint2*)&vtile[n][q * 4];
      uint2 hi = *(const uint2*)&vtile[n][16 + q * 4];
      uint4 pk = {lo.x, lo.y, hi.x, hi.y};
      *(uint4*)&dst[q * 8] = pk;
    }
  }
}

// ---------------------------------------------------------------------------
// attn v5: f16 pipeline, S^T + in-lane P, l via ones-column MFMA, bias -14
// folded into S C-init. Block = (bh, 64-q tile), 4 waves x 512-key split.
// Hot loop: zero LDS, zero cross-lane, 3 VALU/score + 1 cvt_pkrtz/pair.
// ---------------------------------------------------------------------------
__global__ __launch_bounds__(256, 3) void attn(
    const unsigned short* __restrict__ Kb, const unsigned short* __restrict__ Vs,
    float* __restrict__ out) {
  // cbuf rows: 64 d-rows (o) + 16 l-rows; cols 64 q + 4 pad (16B-aligned rows)
  __shared__ __align__(16) float cbuf[2][80 * 68];
  const int tid = threadIdx.x, wave = tid >> 6, lane = tid & 63;
  const int l15 = lane & 15, quad = lane >> 4;
  const int bh = blockIdx.x & 31;  // all 32 q-tiles of a bh share an XCD
  const int qt = blockIdx.x >> 5;
  const int q0 = qt * 64;
  const unsigned short* Kbh = Kb + (size_t)bh * T_SEQ * DH;
  const unsigned short* Vbh = Vs + (size_t)bh * DH * T_SEQ;

  // Q B-frags for the 64 shared q-rows
  f16x8 bq[4][2];
#pragma unroll
  for (int nt = 0; nt < 4; nt++)
#pragma unroll
    for (int kc = 0; kc < 2; kc++)
      bq[nt][kc] = *(const f16x8*)&Kbh[(size_t)(q0 + nt * 16 + l15) * DH + kc * 32 + quad * 8];

  f16x8 ones;
#pragma unroll
  for (int j = 0; j < 8; j++) ones[j] = (_Float16)1.0f;

  f32x4 o[4][4], lacc[4];
#pragma unroll
  for (int mt = 0; mt < 4; mt++) {
    lacc[mt] = (f32x4){0.f, 0.f, 0.f, 0.f};
#pragma unroll
    for (int dt = 0; dt < 4; dt++) o[mt][dt] = (f32x4){0.f, 0.f, 0.f, 0.f};
  }
  const f32x4 cinit = {-14.f, -14.f, -14.f, -14.f};  // exp2 bias; cancels in softmax

  const int sbase = wave * 512;
  f16x8 ka[2][2], vb[4];
#pragma unroll
  for (int mt = 0; mt < 2; mt++)
#pragma unroll
    for (int kc = 0; kc < 2; kc++)
      ka[mt][kc] = *(const f16x8*)&Kbh[(size_t)(sbase + mt * 16 + l15) * DH + kc * 32 + quad * 8];
#pragma unroll
  for (int dt = 0; dt < 4; dt++)
    vb[dt] = *(const f16x8*)&Vbh[(size_t)(dt * 16 + l15) * T_SEQ + sbase + quad * 8];

  for (int it = 0; it < 16; it++) {
    const int nxt = sbase + ((it == 15) ? it : it + 1) * 32;
    // S^T - 14 = K.Q^T + cinit : 32 keys x 64 q
    f32x4 s[2][4];
#pragma unroll
    for (int mt = 0; mt < 2; mt++)
#pragma unroll
      for (int nt = 0; nt < 4; nt++) {
        f32x4 c = __builtin_amdgcn_mfma_f32_16x16x32_f16(ka[mt][0], bq[nt][0], cinit, 0, 0, 0);
        c = __builtin_amdgcn_mfma_f32_16x16x32_f16(ka[mt][1], bq[nt][1], c, 0, 0, 0);
        s[mt][nt] = c;
      }
    // prefetch next K frags (ka dead after S phase)
#pragma unroll
    for (int mt = 0; mt < 2; mt++)
#pragma unroll
      for (int kc = 0; kc < 2; kc++)
        ka[mt][kc] = *(const f16x8*)&Kbh[(size_t)(nxt + mt * 16 + l15) * DH + kc * 32 + quad * 8];

    // p = exp2(max(u, 0.2u - 11.2)) where u = S-14; pack pairs via cvt_pkrtz
    unsigned int pk[2][4][2];
#pragma unroll
    for (int mt = 0; mt < 2; mt++)
#pragma unroll
      for (int nt = 0; nt < 4; nt++) {
        float e[4];
#pragma unroll
        for (int r = 0; r < 4; r++) {
          float u = s[mt][nt][r];
          e[r] = __builtin_amdgcn_exp2f(fmaxf(u, __builtin_fmaf(0.2f, u, -11.2f)));
        }
        pk[mt][nt][0] = __builtin_bit_cast(unsigned int, __builtin_amdgcn_cvt_pkrtz(e[0], e[1]));
        pk[mt][nt][1] = __builtin_bit_cast(unsigned int, __builtin_amdgcn_cvt_pkrtz(e[2], e[3]));
      }

    // O += P V ; l += P 1  (A-frag in-lane via sigma; B ones = no load)
#pragma unroll
    for (int mq = 0; mq < 4; mq++) {
      uint4 pu = {pk[0][mq][0], pk[0][mq][1], pk[1][mq][0], pk[1][mq][1]};
      f16x8 pa = __builtin_bit_cast(f16x8, pu);
#pragma unroll
      for (int dt = 0; dt < 4; dt++)
        o[mq][dt] = __builtin_amdgcn_mfma_f32_16x16x32_f16(pa, vb[dt], o[mq][dt], 0, 0, 0);
      lacc[mq] = __builtin_amdgcn_mfma_f32_16x16x32_f16(pa, ones, lacc[mq], 0, 0, 0);
    }
    // prefetch next V frags (vb dead after PV phase)
#pragma unroll
    for (int dt = 0; dt < 4; dt++)
      vb[dt] = *(const f16x8*)&Vbh[(size_t)(dt * 16 + l15) * T_SEQ + nxt + quad * 8];
  }

  // ---- combine 4 wave-partials (o rows 0-63, l rows 64-79) ----
  __syncthreads();  // B1 (pair with R4 tree structure)
  if (wave >= 2) {
    float* cb = cbuf[wave - 2];
#pragma unroll
    for (int mt = 0; mt < 4; mt++) {
#pragma unroll
      for (int dt = 0; dt < 4; dt++)
        *(f32x4*)&cb[(dt * 16 + l15) * 68 + mt * 16 + quad * 4] = o[mt][dt];
      *(f32x4*)&cb[(64 + l15) * 68 + mt * 16 + quad * 4] = lacc[mt];
    }
  }
  __syncthreads();  // B2
  if (wave < 2) {
    float* cb = cbuf[wave];
#pragma unroll
    for (int mt = 0; mt < 4; mt++) {
#pragma unroll
      for (int dt = 0; dt < 4; dt++)
        o[mt][dt] += *(const f32x4*)&cb[(dt * 16 + l15) * 68 + mt * 16 + quad * 4];
      lacc[mt] += *(const f32x4*)&cb[(64 + l15) * 68 + mt * 16 + quad * 4];
    }
  }
  __syncthreads();  // B3
  if (wave == 1) {
#pragma unroll
    for (int mt = 0; mt < 4; mt++) {
#pragma unroll
      for (int dt = 0; dt < 4; dt++)
        *(f32x4*)&cbuf[0][(dt * 16 + l15) * 68 + mt * 16 + quad * 4] = o[mt][dt];
      *(f32x4*)&cbuf[0][(64 + l15) * 68 + mt * 16 + quad * 4] = lacc[mt];
    }
  }
  __syncthreads();  // B4
  if (wave == 0) {
#pragma unroll
    for (int mt = 0; mt < 4; mt++) {
#pragma unroll
      for (int dt = 0; dt < 4; dt++)
        o[mt][dt] += *(const f32x4*)&cbuf[0][(dt * 16 + l15) * 68 + mt * 16 + quad * 4];
      lacc[mt] += *(const f32x4*)&cbuf[0][(64 + l15) * 68 + mt * 16 + quad * 4];
    }
    const int b = bh >> 2, head = bh & 3;
#pragma unroll
    for (int mt = 0; mt < 4; mt++) {
#pragma unroll
      for (int r = 0; r < 4; r++) {
        float iv = 1.0f / lacc[mt][r];  // l in-lane, row-aligned with o
        int q = mt * 16 + quad * 4 + r;
        float* dst = &out[((size_t)b * T_SEQ + q0 + q) * 256 + head * 64];
#pragma unroll
        for (int dt = 0; dt < 4; dt++) dst[dt * 16 + l15] = o[mt][dt][r] * iv;
      }
    }
  }
}

extern "C" void kernel_launch(void* const* d_in, const int* in_sizes, int n_in,
                              void* d_out, int out_size, void* d_ws, size_t ws_size,
                              hipStream_t stream) {
  const float* h = (const float*)d_in[0];
  const float* W = (const float*)d_in[1];
  float* out = (float*)d_out;
  unsigned short* Kb = (unsigned short*)d_ws;            // 8 MB
  unsigned short* Vs = Kb + (size_t)32 * T_SEQ * DH;     // 8 MB, sigma-permuted V^T (f16)
  unsigned short* WtHi = (unsigned short*)out;           // head of d_out; attn overwrites later
  unsigned short* WtLo = WtHi + 65536;
  prep_w<<<32, 256, 0, stream>>>(W, WtHi, WtLo);
  wh_gemm<<<512, 256, 0, stream>>>(h, WtHi, WtLo, Kb, Vs);
  attn<<<1024, 256, 0, stream>>>(Kb, Vs, out);
}

// Round 6
// 173.594 us; speedup vs baseline: 1.4570x; 1.4570x over previous
//
#include <hip/hip_runtime.h>

#define T_SEQ 2048
#define NH 4
#define DH 64

typedef __bf16 bf16x8 __attribute__((ext_vector_type(8)));
typedef _Float16 f16x8 __attribute__((ext_vector_type(8)));
typedef float f32x4 __attribute__((ext_vector_type(4)));
typedef unsigned short u16x8 __attribute__((ext_vector_type(8)));

__device__ __forceinline__ unsigned short f2bf_rne(float x) {
  unsigned int u = __builtin_bit_cast(unsigned int, x);
  u += 0x7fffu + ((u >> 16) & 1u);
  return (unsigned short)(u >> 16);
}
__device__ __forceinline__ float bf2f(unsigned short s) {
  unsigned int u = ((unsigned int)s) << 16;
  return __builtin_bit_cast(float, u);
}
__device__ __forceinline__ unsigned short f2h(float x) {
  _Float16 h = (_Float16)x;  // v_cvt_f16_f32, RNE
  return __builtin_bit_cast(unsigned short, h);
}

// ---------------------------------------------------------------------------
// prep_w: transpose + hi/lo split W (256x256 f32) -> WtHi/WtLo [n][k] bf16.
// ---------------------------------------------------------------------------
__global__ void prep_w(const float* __restrict__ W,
                       unsigned short* __restrict__ WtHi,
                       unsigned short* __restrict__ WtLo) {
  __shared__ float ls[32][65];
  const int tid = threadIdx.x;
  const int k0 = (blockIdx.x >> 2) * 32;
  const int n0 = (blockIdx.x & 3) * 64;
#pragma unroll
  for (int i = 0; i < 8; i++) {
    int e = i * 256 + tid;
    int r = e >> 6, c = e & 63;
    ls[r][c] = W[(k0 + r) * 256 + n0 + c];
  }
  __syncthreads();
  const int n = tid & 63;
  const int part = tid >> 6;
  u16x8 vh, vl;
#pragma unroll
  for (int j = 0; j < 8; j++) {
    float w = ls[part * 8 + j][n];
    unsigned short h16 = f2bf_rne(w);
    vh[j] = h16;
    vl[j] = f2bf_rne(w - bf2f(h16));
  }
  size_t dst = (size_t)(n0 + n) * 256 + k0 + part * 8;
  *(u16x8*)&WtHi[dst] = vh;
  *(u16x8*)&WtLo[dst] = vl;
}

// ---------------------------------------------------------------------------
// wh_gemm: Wh = h @ W via split-bf16 MFMA (3-term, ~fp32 accurate).
//   Kb[bh][t][d] = f16(Wh * sqrt(log2e/8))   (Q and K)
//   Vs[bh][d][sigma(t)] = f16(Wh)            (PV B-operand, key-permuted)
// ---------------------------------------------------------------------------
__global__ __launch_bounds__(256, 2) void wh_gemm(
    const float* __restrict__ h,
    const unsigned short* __restrict__ WtHi,
    const unsigned short* __restrict__ WtLo,
    unsigned short* __restrict__ Kb, unsigned short* __restrict__ Vs) {
  __shared__ __align__(16) unsigned short ktile[32][272];
  __shared__ __align__(16) unsigned short vtile[256][40];
  const int tid = threadIdx.x;
  const int wave = tid >> 6, lane = tid & 63, l15 = lane & 15, quad = lane >> 4;
  const int m0b = blockIdx.x * 32;
  const int m0 = m0b + (wave & 1) * 16;
  const int n0w = (wave >> 1) * 128;
  f32x4 acc[8];
#pragma unroll
  for (int nt = 0; nt < 8; nt++) acc[nt] = (f32x4){0.f, 0.f, 0.f, 0.f};

  for (int kc = 0; kc < 8; kc++) {
    const float4* hp = (const float4*)&h[(size_t)(m0 + l15) * 256 + kc * 32 + quad * 8];
    float4 a0 = hp[0], a1 = hp[1];
    float xs[8] = {a0.x, a0.y, a0.z, a0.w, a1.x, a1.y, a1.z, a1.w};
    u16x8 ah, al;
#pragma unroll
    for (int j = 0; j < 8; j++) {
      unsigned short h16 = f2bf_rne(xs[j]);
      ah[j] = h16;
      al[j] = f2bf_rne(xs[j] - bf2f(h16));
    }
    bf16x8 ahi = __builtin_bit_cast(bf16x8, ah);
    bf16x8 alo = __builtin_bit_cast(bf16x8, al);
#pragma unroll
    for (int nt = 0; nt < 8; nt++) {
      size_t wb = (size_t)(n0w + nt * 16 + l15) * 256 + kc * 32 + quad * 8;
      bf16x8 bhi = *(const bf16x8*)&WtHi[wb];
      bf16x8 blo = *(const bf16x8*)&WtLo[wb];
      acc[nt] = __builtin_amdgcn_mfma_f32_16x16x32_bf16(ahi, bhi, acc[nt], 0, 0, 0);
      acc[nt] = __builtin_amdgcn_mfma_f32_16x16x32_bf16(alo, bhi, acc[nt], 0, 0, 0);
      acc[nt] = __builtin_amdgcn_mfma_f32_16x16x32_bf16(ahi, blo, acc[nt], 0, 0, 0);
    }
  }
  const float s1 = 0.424664717f;  // sqrt(log2(e)/8)
  const int tl = (wave & 1) * 16 + quad * 4;
#pragma unroll
  for (int nt = 0; nt < 8; nt++) {
    int n = n0w + nt * 16 + l15;
    ushort4 vp;
#pragma unroll
    for (int r = 0; r < 4; r++) {
      float v = acc[nt][r];
      ktile[tl + r][n] = f2h(v * s1);
      ((unsigned short*)&vp)[r] = f2h(v);
    }
    *(uint2*)&vtile[n][tl] = __builtin_bit_cast(uint2, vp);
  }
  __syncthreads();
  {  // Kb out: 4 x b128 stores (natural t order)
    int t = tid >> 3, seg = tid & 7;
    int m = m0b + t, b = m >> 11, tt = m & 2047;
    int head = seg >> 1, d0 = (seg & 1) * 32;
    unsigned short* dst = &Kb[((size_t)(b * NH + head) * T_SEQ + tt) * DH + d0];
#pragma unroll
    for (int q = 0; q < 4; q++)
      *(u16x8*)&dst[q * 8] = *(const u16x8*)&ktile[t][seg * 32 + q * 8];
  }
  {  // Vs out: sigma order (pos g*32+quad*8+half*4+j <-> t g*32+half*16+quad*4+j)
    int n = tid, head = n >> 6, d = n & 63;
    int b = m0b >> 11, t0 = m0b & 2047;
    unsigned short* dst = &Vs[((size_t)(b * NH + head) * DH + d) * T_SEQ + t0];
#pragma unroll
    for (int q = 0; q < 4; q++) {
      uint2 lo = *(const uint2*)&vtile[n][q * 4];
      uint2 hi = *(const uint2*)&vtile[n][16 + q * 4];
      uint4 pk = {lo.x, lo.y, hi.x, hi.y};
      *(uint4*)&dst[q * 8] = pk;
    }
  }
}

// ---------------------------------------------------------------------------
// attn v6: f16, S^T + in-lane P, bias -14 in C-init, per-nt fused pipeline
// (S-pair MFMA -> exp/pack -> PV immediately) to minimize live temps so the
// allocator keeps all VALU-touched values in arch VGPRs (R5 spilled; R4
// thrashed accvgpr moves). o accumulators are MFMA-only -> AGPR-eligible.
// Block = (bh, 64-q tile), 4 waves x 512-key split. Hot loop: zero LDS.
// ---------------------------------------------------------------------------
__global__ __launch_bounds__(256, 3) void attn(
    const unsigned short* __restrict__ Kb, const unsigned short* __restrict__ Vs,
    float* __restrict__ out) {
  __shared__ __align__(16) float cbuf[2][64 * 68];
  __shared__ float lbuf[4][64];
  __shared__ float inv_s[64];
  const int tid = threadIdx.x, wave = tid >> 6, lane = tid & 63;
  const int l15 = lane & 15, quad = lane >> 4;
  const int bh = blockIdx.x & 31;  // all 32 q-tiles of a bh share an XCD
  const int qt = blockIdx.x >> 5;
  const int q0 = qt * 64;
  const unsigned short* Kbh = Kb + (size_t)bh * T_SEQ * DH;
  const unsigned short* Vbh = Vs + (size_t)bh * DH * T_SEQ;

  // Q B-frags for the 64 shared q-rows (loop-invariant, 32 regs)
  f16x8 bq[4][2];
#pragma unroll
  for (int nt = 0; nt < 4; nt++)
#pragma unroll
    for (int kc = 0; kc < 2; kc++)
      bq[nt][kc] = *(const f16x8*)&Kbh[(size_t)(q0 + nt * 16 + l15) * DH + kc * 32 + quad * 8];

  f32x4 o[4][4];
  float lsum[4] = {0.f, 0.f, 0.f, 0.f};
#pragma unroll
  for (int mt = 0; mt < 4; mt++)
#pragma unroll
    for (int dt = 0; dt < 4; dt++) o[mt][dt] = (f32x4){0.f, 0.f, 0.f, 0.f};
  const f32x4 cinit = {-14.f, -14.f, -14.f, -14.f};  // exp2 bias; cancels in softmax

  const int sbase = wave * 512;
  f16x8 ka[2][2], vb[4];
#pragma unroll
  for (int mt = 0; mt < 2; mt++)
#pragma unroll
    for (int kc = 0; kc < 2; kc++)
      ka[mt][kc] = *(const f16x8*)&Kbh[(size_t)(sbase + mt * 16 + l15) * DH + kc * 32 + quad * 8];
#pragma unroll
  for (int dt = 0; dt < 4; dt++)
    vb[dt] = *(const f16x8*)&Vbh[(size_t)(dt * 16 + l15) * T_SEQ + sbase + quad * 8];

  for (int it = 0; it < 16; it++) {
    const int nxt = sbase + ((it == 15) ? it : it + 1) * 32;
#pragma unroll
    for (int nt = 0; nt < 4; nt++) {
      // S^T pair for q-group nt: keys [0:16) and [16:32) of this 32-key tile
      f32x4 s0 = __builtin_amdgcn_mfma_f32_16x16x32_f16(ka[0][0], bq[nt][0], cinit, 0, 0, 0);
      s0 = __builtin_amdgcn_mfma_f32_16x16x32_f16(ka[0][1], bq[nt][1], s0, 0, 0, 0);
      f32x4 s1 = __builtin_amdgcn_mfma_f32_16x16x32_f16(ka[1][0], bq[nt][0], cinit, 0, 0, 0);
      s1 = __builtin_amdgcn_mfma_f32_16x16x32_f16(ka[1][1], bq[nt][1], s1, 0, 0, 0);

      // p = exp2(max(u, 0.2u - 11.2)), u = S - 14
      float e0, e1, e2, e3, f0, f1, f2, f3;
      {
        float u;
        u = s0[0]; e0 = __builtin_amdgcn_exp2f(fmaxf(u, __builtin_fmaf(0.2f, u, -11.2f)));
        u = s0[1]; e1 = __builtin_amdgcn_exp2f(fmaxf(u, __builtin_fmaf(0.2f, u, -11.2f)));
        u = s0[2]; e2 = __builtin_amdgcn_exp2f(fmaxf(u, __builtin_fmaf(0.2f, u, -11.2f)));
        u = s0[3]; e3 = __builtin_amdgcn_exp2f(fmaxf(u, __builtin_fmaf(0.2f, u, -11.2f)));
        u = s1[0]; f0 = __builtin_amdgcn_exp2f(fmaxf(u, __builtin_fmaf(0.2f, u, -11.2f)));
        u = s1[1]; f1 = __builtin_amdgcn_exp2f(fmaxf(u, __builtin_fmaf(0.2f, u, -11.2f)));
        u = s1[2]; f2 = __builtin_amdgcn_exp2f(fmaxf(u, __builtin_fmaf(0.2f, u, -11.2f)));
        u = s1[3]; f3 = __builtin_amdgcn_exp2f(fmaxf(u, __builtin_fmaf(0.2f, u, -11.2f)));
      }
      lsum[nt] += ((e0 + e1) + (e2 + e3)) + ((f0 + f1) + (f2 + f3));
      uint4 pu;
      pu.x = __builtin_bit_cast(unsigned int, __builtin_amdgcn_cvt_pkrtz(e0, e1));
      pu.y = __builtin_bit_cast(unsigned int, __builtin_amdgcn_cvt_pkrtz(e2, e3));
      pu.z = __builtin_bit_cast(unsigned int, __builtin_amdgcn_cvt_pkrtz(f0, f1));
      pu.w = __builtin_bit_cast(unsigned int, __builtin_amdgcn_cvt_pkrtz(f2, f3));
      f16x8 pa = __builtin_bit_cast(f16x8, pu);  // sigma-matched A-frag, in-lane

      if (nt == 3) {  // ka dead after this group's S phase -> prefetch next
#pragma unroll
        for (int mt = 0; mt < 2; mt++)
#pragma unroll
          for (int kc = 0; kc < 2; kc++)
            ka[mt][kc] = *(const f16x8*)&Kbh[(size_t)(nxt + mt * 16 + l15) * DH + kc * 32 + quad * 8];
      }
      // O(q-group nt) += P V
#pragma unroll
      for (int dt = 0; dt < 4; dt++)
        o[nt][dt] = __builtin_amdgcn_mfma_f32_16x16x32_f16(pa, vb[dt], o[nt][dt], 0, 0, 0);
      if (nt == 3) {  // vb dead after last PV -> prefetch next
#pragma unroll
        for (int dt = 0; dt < 4; dt++)
          vb[dt] = *(const f16x8*)&Vbh[(size_t)(dt * 16 + l15) * T_SEQ + nxt + quad * 8];
      }
    }
  }

  // ---- combine 4 wave-partials (R4-verified tree) ----
#pragma unroll
  for (int nt = 0; nt < 4; nt++) {
    float l = lsum[nt];
    l += __shfl_xor(l, 16, 64);
    l += __shfl_xor(l, 32, 64);
    if (quad == 0) lbuf[wave][nt * 16 + l15] = l;
  }
  __syncthreads();  // B1
  if (wave >= 2) {
    float* cb = cbuf[wave - 2];
#pragma unroll
    for (int mt = 0; mt < 4; mt++)
#pragma unroll
      for (int dt = 0; dt < 4; dt++)
        *(f32x4*)&cb[(dt * 16 + l15) * 68 + mt * 16 + quad * 4] = o[mt][dt];
  }
  if (wave == 0) {
    float s = lbuf[0][lane] + lbuf[1][lane] + lbuf[2][lane] + lbuf[3][lane];
    inv_s[lane] = 1.0f / s;
  }
  __syncthreads();  // B2
  if (wave < 2) {
    float* cb = cbuf[wave];
#pragma unroll
    for (int mt = 0; mt < 4; mt++)
#pragma unroll
      for (int dt = 0; dt < 4; dt++)
        o[mt][dt] += *(const f32x4*)&cb[(dt * 16 + l15) * 68 + mt * 16 + quad * 4];
  }
  __syncthreads();  // B3
  if (wave == 1) {
#pragma unroll
    for (int mt = 0; mt < 4; mt++)
#pragma unroll
      for (int dt = 0; dt < 4; dt++)
        *(f32x4*)&cbuf[0][(dt * 16 + l15) * 68 + mt * 16 + quad * 4] = o[mt][dt];
  }
  __syncthreads();  // B4
  if (wave == 0) {
#pragma unroll
    for (int mt = 0; mt < 4; mt++)
#pragma unroll
      for (int dt = 0; dt < 4; dt++)
        o[mt][dt] += *(const f32x4*)&cbuf[0][(dt * 16 + l15) * 68 + mt * 16 + quad * 4];
    const int b = bh >> 2, head = bh & 3;
#pragma unroll
    for (int mt = 0; mt < 4; mt++) {
#pragma unroll
      for (int r = 0; r < 4; r++) {
        float iv = inv_s[mt * 16 + quad * 4 + r];
        int q = mt * 16 + quad * 4 + r;
        float* dst = &out[((size_t)b * T_SEQ + q0 + q) * 256 + head * 64];
#pragma unroll
        for (int dt = 0; dt < 4; dt++) dst[dt * 16 + l15] = o[mt][dt][r] * iv;
      }
    }
  }
}

extern "C" void kernel_launch(void* const* d_in, const int* in_sizes, int n_in,
                              void* d_out, int out_size, void* d_ws, size_t ws_size,
                              hipStream_t stream) {
  const float* h = (const float*)d_in[0];
  const float* W = (const float*)d_in[1];
  float* out = (float*)d_out;
  unsigned short* Kb = (unsigned short*)d_ws;            // 8 MB (f16)
  unsigned short* Vs = Kb + (size_t)32 * T_SEQ * DH;     // 8 MB, sigma-permuted V^T (f16)
  unsigned short* WtHi = (unsigned short*)out;           // head of d_out; attn overwrites later
  unsigned short* WtLo = WtHi + 65536;
  prep_w<<<32, 256, 0, stream>>>(W, WtHi, WtLo);
  wh_gemm<<<512, 256, 0, stream>>>(h, WtHi, WtLo, Kb, Vs);
  attn<<<1024, 256, 0, stream>>>(Kb, Vs, out);
}